// Round 12
// baseline (211.564 us; speedup 1.0000x reference)
//
#include <hip/hip_runtime.h>
#include <math.h>

#define B_   256
#define S_   200
#define NQ_  400
#define K_   4
#define M_   50
#define KD_  50
#define VD_  200
#define FD_  50
#define T_   (B_*S_)   // 51200 tokens
#define NE_  ((NQ_+1)*K_)   // 1604 distinct (q,r) rows

// ---------------------------------------------------------------------------
// kA1: corr LUT [401][50]. corr is a pure function of q.
// ---------------------------------------------------------------------------
__global__ __launch_bounds__(256) void kA1_corrlut(
    const float* __restrict__ q_tab, const float* __restrict__ key_mem,
    const float* __restrict__ W_qk, const float* __restrict__ b_qk,
    float* __restrict__ clut)
{
    const int wave = threadIdx.x >> 6;
    const int lane = threadIdx.x & 63;
    int qi = blockIdx.x * 4 + wave;
    const bool valid = (qi <= NQ_);
    if (qi > NQ_) qi = NQ_;

    __shared__ float sqk[4][KD_];
    const float* qe = q_tab + (size_t)qi * KD_;
    if (lane < KD_) {
        float acc = b_qk[lane];
#pragma unroll 10
        for (int k = 0; k < KD_; ++k)
            acc += qe[k] * W_qk[k * KD_ + lane];
        sqk[wave][lane] = tanhf(acc);
    }
    __syncthreads();

    float c = -INFINITY;
    if (lane < M_) {
        float acc = 0.0f;
#pragma unroll 10
        for (int k = 0; k < KD_; ++k)
            acc += sqk[wave][k] * key_mem[lane * KD_ + k];
        c = acc;
    }
    float mx = c;
#pragma unroll
    for (int off = 32; off; off >>= 1) mx = fmaxf(mx, __shfl_xor(mx, off));
    float e = (lane < M_) ? expf(c - mx) : 0.0f;
    float sm = e;
#pragma unroll
    for (int off = 32; off; off >>= 1) sm += __shfl_xor(sm, off);
    if (valid && lane < M_) clut[(size_t)qi * M_ + lane] = e / sm;
}

// ---------------------------------------------------------------------------
// kA2: erase/add LUT [1604][200]. One block per q, all 4 r-variants.
// ---------------------------------------------------------------------------
__global__ __launch_bounds__(256) void kA2_ealut(
    const float* __restrict__ W_v3, const float* __restrict__ b_v,
    const float* __restrict__ W_e, const float* __restrict__ b_e,
    const float* __restrict__ W_a, const float* __restrict__ b_a,
    float* __restrict__ elut, float* __restrict__ alut)
{
    __shared__ __align__(16) float sV[VD_][4];   // [k][r]
    const int qi  = blockIdx.x;                  // 0..400
    const int tid = threadIdx.x;
    const float qm = (qi > 0) ? 1.0f : 0.0f;
    int idx = qi - 1;
    if (idx < 0) idx = 0;

    float wc[4][4];
#pragma unroll
    for (int r = 0; r < 4; ++r)
#pragma unroll
        for (int k = 0; k < 4; ++k) {
            float dist = fabsf((float)k - (float)r) / (float)(K_ - 1);
            float w = 1.0f - dist;
            wc[r][k] = (w > 0.0f) ? w : 0.0f;
        }

    if (tid < VD_) {
        float w3[4];
#pragma unroll
        for (int k = 0; k < 4; ++k)
            w3[k] = W_v3[((size_t)k * NQ_ + idx) * VD_ + tid];
        float bv = b_v[tid];
#pragma unroll
        for (int r = 0; r < 4; ++r) {
            float s = wc[r][0]*w3[0] + wc[r][1]*w3[1] + wc[r][2]*w3[2] + wc[r][3]*w3[3];
            sV[tid][r] = bv + qm * s;
        }
    }
    __syncthreads();

    if (tid < VD_) {
        const int c = tid;
        float accE[4] = {0.f,0.f,0.f,0.f}, accA[4] = {0.f,0.f,0.f,0.f};
#pragma unroll 4
        for (int k = 0; k < VD_; ++k) {
            float we = W_e[(size_t)k * VD_ + c];
            float wa = W_a[(size_t)k * VD_ + c];
            float4 v = *(const float4*)&sV[k][0];
            float vv[4] = {v.x, v.y, v.z, v.w};
#pragma unroll
            for (int r = 0; r < 4; ++r) {
                accE[r] = fmaf(vv[r], we, accE[r]);
                accA[r] = fmaf(vv[r], wa, accA[r]);
            }
        }
        const float be = b_e[c], ba = b_a[c];
#pragma unroll
        for (int r = 0; r < 4; ++r) {
            const size_t row = (size_t)qi * K_ + r;
            elut[row * VD_ + c] = 1.0f / (1.0f + expf(-(accE[r] + be)));
            alut[row * VD_ + c] = tanhf(accA[r] + ba);
        }
    }
}

// ---------------------------------------------------------------------------
// kB v9: barrier-free 2-group scan; corr weights via the SCALAR pipe.
// v6 (1 wave/SIMD) and v8 (2 waves/SIMD) both took ~110us -> the bottleneck
// is the shared per-CU LDS pipe serving ~25 broadcast ds_reads/wave/step.
// w[s][m] is wave-uniform, so read it from clut with a readfirstlane'd
// uniform address -> s_load (SMEM), freeing the LDS pipe entirely. Rows
// s+2/s+3 are prefetched one iteration ahead in registers. e/a keep the
// 4-deep VMEM pipeline; groups write partial reads0/reads1 (k4a sums).
// ---------------------------------------------------------------------------
__global__ __launch_bounds__(512) void kB_scan(
    const int* __restrict__ q_data, const int* __restrict__ r_data,
    const float* __restrict__ init_mem, const float* __restrict__ clut,
    const float* __restrict__ elut, const float* __restrict__ alut,
    float* __restrict__ reads0, float* __restrict__ reads1)
{
    const int b   = blockIdx.x;
    const int tid = threadIdx.x;
    const int j   = tid & 255;
    const int g   = tid >> 8;          // 0 or 1 (uniform per wave)
    const bool act = (j < VD_);
    const int m0  = g * 25;

    __shared__ int sQ[S_], sR[S_];
    for (int i = tid; i < S_; i += 512) {
        sQ[i] = q_data[b * S_ + i];
        sR[i] = r_data[b * S_ + i];
    }

    float mem[25];
    if (act) {
#pragma unroll
        for (int m = 0; m < 25; ++m) mem[m] = init_mem[(m0 + m) * VD_ + j];
    }
    __syncthreads();   // sQ/sR visible — the only barrier

    float* rb = (g == 0 ? reads0 : reads1) + (size_t)b * S_ * VD_;

    // 4-deep e/a register pipeline
    float e0=0,a0=0,e1=0,a1=0,e2=0,a2=0,e3=0,a3=0;
    if (act) {
        size_t i0 = (size_t)(sQ[0]*K_ + sR[0]) * VD_ + j;
        size_t i1 = (size_t)(sQ[1]*K_ + sR[1]) * VD_ + j;
        size_t i2 = (size_t)(sQ[2]*K_ + sR[2]) * VD_ + j;
        size_t i3 = (size_t)(sQ[3]*K_ + sR[3]) * VD_ + j;
        e0 = elut[i0]; a0 = alut[i0];
        e1 = elut[i1]; a1 = alut[i1];
        e2 = elut[i2]; a2 = alut[i2];
        e3 = elut[i3]; a3 = alut[i3];
    }

    // w rows for steps 0,1 — scalar loads (uniform address per wave)
    float wsA[25], wsB[25];
    {
        const int q0 = __builtin_amdgcn_readfirstlane(sQ[0]);
        const int q1 = __builtin_amdgcn_readfirstlane(sQ[1]);
        const float* c0 = clut + (size_t)q0 * M_ + m0;
        const float* c1 = clut + (size_t)q1 * M_ + m0;
#pragma unroll
        for (int i = 0; i < 25; ++i) { wsA[i] = c0[i]; wsB[i] = c1[i]; }
    }

    for (int s = 0; s < S_; s += 2) {
        // prefetch e/a rows s+4, s+5 (VMEM, consumed 2 iterations later)
        float e4=0,a4=0,e5=0,a5=0;
        if (act && s+4 < S_) {
            size_t i4 = (size_t)(sQ[s+4]*K_ + sR[s+4]) * VD_ + j;
            e4 = elut[i4]; a4 = alut[i4];
        }
        if (act && s+5 < S_) {
            size_t i5 = (size_t)(sQ[s+5]*K_ + sR[s+5]) * VD_ + j;
            e5 = elut[i5]; a5 = alut[i5];
        }
        // prefetch w rows s+2, s+3 (scalar pipe, consumed next iteration)
        float wnA[25], wnB[25];
        {
            const int r2 = (s+2 < S_) ? s+2 : S_-1;
            const int r3 = (s+3 < S_) ? s+3 : S_-1;
            const int q2 = __builtin_amdgcn_readfirstlane(sQ[r2]);
            const int q3 = __builtin_amdgcn_readfirstlane(sQ[r3]);
            const float* c2 = clut + (size_t)q2 * M_ + m0;
            const float* c3 = clut + (size_t)q3 * M_ + m0;
#pragma unroll
            for (int i = 0; i < 25; ++i) { wnA[i] = c2[i]; wnB[i] = c3[i]; }
        }

        // step s (uses wsA)
        {
            float ra = 0.f, rc = 0.f;
#pragma unroll
            for (int i = 0; i < 25; i += 2) {
                float w0 = wsA[i];
                ra = fmaf(w0, mem[i], ra);
                float t0 = fmaf(-e0, mem[i], a0);
                mem[i] = fmaf(w0, t0, mem[i]);
                if (i + 1 < 25) {
                    float w1 = wsA[i+1];
                    rc = fmaf(w1, mem[i+1], rc);
                    float t1 = fmaf(-e0, mem[i+1], a0);
                    mem[i+1] = fmaf(w1, t1, mem[i+1]);
                }
            }
            if (act) rb[s * VD_ + j] = ra + rc;
        }
        // step s+1 (uses wsB)
        {
            float ra = 0.f, rc = 0.f;
#pragma unroll
            for (int i = 0; i < 25; i += 2) {
                float w0 = wsB[i];
                ra = fmaf(w0, mem[i], ra);
                float t0 = fmaf(-e1, mem[i], a1);
                mem[i] = fmaf(w0, t0, mem[i]);
                if (i + 1 < 25) {
                    float w1 = wsB[i+1];
                    rc = fmaf(w1, mem[i+1], rc);
                    float t1 = fmaf(-e1, mem[i+1], a1);
                    mem[i+1] = fmaf(w1, t1, mem[i+1]);
                }
            }
            if (act) rb[(s+1) * VD_ + j] = ra + rc;
        }
        // rotate pipelines (static names only)
        e0 = e2; a0 = a2; e1 = e3; a1 = a3;
        e2 = e4; a2 = a4; e3 = e5; a3 = a5;
#pragma unroll
        for (int i = 0; i < 25; ++i) { wsA[i] = wnA[i]; wsB[i] = wnB[i]; }
    }
}

// ---------------------------------------------------------------------------
// k4a: summary GEMM. Stages sAt = reads0 + reads1 (the two scan partials).
// BT=40 -> 1280 blocks. Writes summary transposed summT[c][tok].
// ---------------------------------------------------------------------------
#define BT4A 40
__global__ __launch_bounds__(256) void k4a_summary(
    const int* __restrict__ q_data, const float* __restrict__ q_tab,
    const float* __restrict__ reads0, const float* __restrict__ reads1,
    const float* __restrict__ W_sum, const float* __restrict__ b_sum,
    float* __restrict__ summT)
{
    __shared__ __align__(16) float sAt[25][44];   // [kk][t], pad 44
    __shared__ __align__(16) float sW[25][52];
    __shared__ int sQ[BT4A];

    const int tid  = threadIdx.x;
    const int tok0 = blockIdx.x * BT4A;
    const int ty = tid / 25;        // 0..9 -> token group of 4
    const int tx = tid % 25;        // col pair
    const bool act = (tid < 250);
    const int t0 = ty * 4;

    if (tid < BT4A) sQ[tid] = q_data[tok0 + tid];

    float acc[4][2];
#pragma unroll
    for (int i = 0; i < 4; ++i) { acc[i][0] = 0.f; acc[i][1] = 0.f; }

    for (int kt = 0; kt < 250; kt += 25) {
        __syncthreads();
        for (int i = tid; i < BT4A * 25; i += 256) {
            int t = i / 25, kk = i % 25;
            float v;
            if (kt < VD_) {
                size_t idx = (size_t)(tok0 + t) * VD_ + kt + kk;
                v = reads0[idx] + reads1[idx];
            } else {
                v = q_tab[(size_t)sQ[t] * KD_ + (kt - VD_) + kk];
            }
            sAt[kk][t] = v;
        }
        for (int i = tid; i < 25 * FD_; i += 256) {
            int kk = i / FD_, col = i % FD_;
            sW[kk][col] = W_sum[(size_t)(kt + kk) * FD_ + col];
        }
        __syncthreads();

        if (act) {
#pragma unroll 5
            for (int kk = 0; kk < 25; ++kk) {
                float2 w = *(const float2*)&sW[kk][2 * tx];
                float4 a0 = *(const float4*)&sAt[kk][t0];
                float av[4] = {a0.x, a0.y, a0.z, a0.w};
#pragma unroll
                for (int i = 0; i < 4; ++i) {
                    acc[i][0] = fmaf(av[i], w.x, acc[i][0]);
                    acc[i][1] = fmaf(av[i], w.y, acc[i][1]);
                }
            }
        }
    }

    if (act) {
        const float b0 = b_sum[2 * tx], b1 = b_sum[2 * tx + 1];
#pragma unroll
        for (int i = 0; i < 4; ++i) {
            const size_t tok = tok0 + t0 + i;
            summT[(size_t)(2 * tx)     * T_ + tok] = tanhf(acc[i][0] + b0);
            summT[(size_t)(2 * tx + 1) * T_ + tok] = tanhf(acc[i][1] + b1);
        }
    }
}

// ---------------------------------------------------------------------------
// k4b: per-token head. One thread per token; summT reads coalesced; W
// vectors wave-uniform; no shfl, no LDS.
// ---------------------------------------------------------------------------
__global__ __launch_bounds__(256) void k4b_head(
    const int* __restrict__ q_data, const float* __restrict__ q_tab,
    const float* __restrict__ summT,
    const float* __restrict__ W_ab, const float* __restrict__ b_ab,
    const float* __restrict__ W_th, const float* __restrict__ b_th,
    const float* __restrict__ W_disc, const float* __restrict__ b_disc,
    float* __restrict__ out)
{
    const int tok = blockIdx.x * 256 + threadIdx.x;
    const int q = q_data[tok];
    const float* qe = q_tab + (size_t)q * KD_;

    float v_ab = 0.f, v_d = 0.f, v_t0 = 0.f, v_t1 = 0.f, v_t2 = 0.f;
#pragma unroll 10
    for (int c = 0; c < FD_; ++c) {
        float s  = summT[(size_t)c * T_ + tok];
        float qv = qe[c];
        v_ab = fmaf(s,  W_ab[c],        v_ab);
        v_d  = fmaf(s,  W_disc[c],      v_d);
        v_d  = fmaf(qv, W_disc[FD_ + c], v_d);
        v_t0 = fmaf(qv, W_th[c * 3 + 0], v_t0);
        v_t1 = fmaf(qv, W_th[c * 3 + 1], v_t1);
        v_t2 = fmaf(qv, W_th[c * 3 + 2], v_t2);
    }

    float theta = 3.0f * (v_ab + b_ab[0]);
    float xd = v_d + b_disc[0];
    float alpha = fmaxf(xd, 0.0f) + log1pf(expf(-fabsf(xd)));
    float beta0 = tanhf(v_t0 + b_th[0]);
    float beta1 = tanhf(v_t1 + b_th[1]);
    float beta2 = tanhf(v_t2 + b_th[2]);
    float c1 = alpha * (theta - beta0);
    float c2 = c1 + alpha * (theta - beta1);
    float c3 = c2 + alpha * (theta - beta2);
    float mx = fmaxf(fmaxf(0.0f, c1), fmaxf(c2, c3));
    float e0 = expf(0.0f - mx), e1 = expf(c1 - mx),
          e2 = expf(c2 - mx), e3 = expf(c3 - mx);
    float s4 = e0 + e1 + e2 + e3;
    float4 o = make_float4(e0 / s4, e1 / s4, e2 / s4, e3 / s4);
    *(float4*)&out[(size_t)tok * 4] = o;
}

// ---------------------------------------------------------------------------
extern "C" void kernel_launch(void* const* d_in, const int* in_sizes, int n_in,
                              void* d_out, int out_size, void* d_ws, size_t ws_size,
                              hipStream_t stream) {
    const int*   q_data   = (const int*)  d_in[0];
    const int*   r_data   = (const int*)  d_in[1];
    const float* q_tab    = (const float*)d_in[2];
    const float* key_mem  = (const float*)d_in[3];
    const float* init_mem = (const float*)d_in[4];
    const float* W_qk     = (const float*)d_in[5];
    const float* b_qk     = (const float*)d_in[6];
    const float* W_v3     = (const float*)d_in[7];
    const float* b_v      = (const float*)d_in[8];
    const float* W_e      = (const float*)d_in[9];
    const float* b_e      = (const float*)d_in[10];
    const float* W_a      = (const float*)d_in[11];
    const float* b_a      = (const float*)d_in[12];
    const float* W_sum    = (const float*)d_in[13];
    const float* b_sum    = (const float*)d_in[14];
    const float* W_ab     = (const float*)d_in[15];
    const float* b_ab     = (const float*)d_in[16];
    const float* W_th     = (const float*)d_in[17];
    const float* b_th     = (const float*)d_in[18];
    const float* W_disc   = (const float*)d_in[19];
    const float* b_disc   = (const float*)d_in[20];

    float* ws     = (float*)d_ws;
    float* reads0 = ws;                                   // T*VD
    float* reads1 = reads0 + (size_t)T_ * VD_;            // T*VD
    float* clut   = reads1 + (size_t)T_ * VD_;            // 401*50
    float* elut   = clut + (size_t)(NQ_ + 1) * M_;        // 1604*200
    float* alut   = elut + (size_t)NE_ * VD_;             // 1604*200
    float* summT  = alut + (size_t)NE_ * VD_;             // 50*T
    // total ~23.7M floats = 95 MB

    kA1_corrlut<<<(NQ_ + 4) / 4, 256, 0, stream>>>(q_tab, key_mem, W_qk, b_qk, clut);
    kA2_ealut<<<NQ_ + 1, 256, 0, stream>>>(W_v3, b_v, W_e, b_e, W_a, b_a, elut, alut);
    kB_scan<<<B_, 512, 0, stream>>>(q_data, r_data, init_mem, clut, elut, alut,
                                    reads0, reads1);
    k4a_summary<<<T_ / BT4A, 256, 0, stream>>>(q_data, q_tab, reads0, reads1,
                                               W_sum, b_sum, summT);
    k4b_head<<<T_ / 256, 256, 0, stream>>>(q_data, q_tab, summT,
                                           W_ab, b_ab, W_th, b_th, W_disc, b_disc,
                                           (float*)d_out);
}

// Round 13
// 194.167 us; speedup vs baseline: 1.0896x; 1.0896x over previous
//
#include <hip/hip_runtime.h>
#include <math.h>

#define B_   256
#define S_   200
#define NQ_  400
#define K_   4
#define M_   50
#define KD_  50
#define VD_  200
#define FD_  50
#define T_   (B_*S_)   // 51200 tokens
#define NE_  ((NQ_+1)*K_)   // 1604 distinct (q,r) rows

// ---------------------------------------------------------------------------
// kA1: corr LUT [401][50]. corr is a pure function of q.
// ---------------------------------------------------------------------------
__global__ __launch_bounds__(256) void kA1_corrlut(
    const float* __restrict__ q_tab, const float* __restrict__ key_mem,
    const float* __restrict__ W_qk, const float* __restrict__ b_qk,
    float* __restrict__ clut)
{
    const int wave = threadIdx.x >> 6;
    const int lane = threadIdx.x & 63;
    int qi = blockIdx.x * 4 + wave;
    const bool valid = (qi <= NQ_);
    if (qi > NQ_) qi = NQ_;

    __shared__ float sqk[4][KD_];
    const float* qe = q_tab + (size_t)qi * KD_;
    if (lane < KD_) {
        float acc = b_qk[lane];
#pragma unroll 10
        for (int k = 0; k < KD_; ++k)
            acc += qe[k] * W_qk[k * KD_ + lane];
        sqk[wave][lane] = tanhf(acc);
    }
    __syncthreads();

    float c = -INFINITY;
    if (lane < M_) {
        float acc = 0.0f;
#pragma unroll 10
        for (int k = 0; k < KD_; ++k)
            acc += sqk[wave][k] * key_mem[lane * KD_ + k];
        c = acc;
    }
    float mx = c;
#pragma unroll
    for (int off = 32; off; off >>= 1) mx = fmaxf(mx, __shfl_xor(mx, off));
    float e = (lane < M_) ? expf(c - mx) : 0.0f;
    float sm = e;
#pragma unroll
    for (int off = 32; off; off >>= 1) sm += __shfl_xor(sm, off);
    if (valid && lane < M_) clut[(size_t)qi * M_ + lane] = e / sm;
}

// ---------------------------------------------------------------------------
// kA2: erase/add LUT [1604][200]. One block per q, all 4 r-variants.
// ---------------------------------------------------------------------------
__global__ __launch_bounds__(256) void kA2_ealut(
    const float* __restrict__ W_v3, const float* __restrict__ b_v,
    const float* __restrict__ W_e, const float* __restrict__ b_e,
    const float* __restrict__ W_a, const float* __restrict__ b_a,
    float* __restrict__ elut, float* __restrict__ alut)
{
    __shared__ __align__(16) float sV[VD_][4];   // [k][r]
    const int qi  = blockIdx.x;                  // 0..400
    const int tid = threadIdx.x;
    const float qm = (qi > 0) ? 1.0f : 0.0f;
    int idx = qi - 1;
    if (idx < 0) idx = 0;

    float wc[4][4];
#pragma unroll
    for (int r = 0; r < 4; ++r)
#pragma unroll
        for (int k = 0; k < 4; ++k) {
            float dist = fabsf((float)k - (float)r) / (float)(K_ - 1);
            float w = 1.0f - dist;
            wc[r][k] = (w > 0.0f) ? w : 0.0f;
        }

    if (tid < VD_) {
        float w3[4];
#pragma unroll
        for (int k = 0; k < 4; ++k)
            w3[k] = W_v3[((size_t)k * NQ_ + idx) * VD_ + tid];
        float bv = b_v[tid];
#pragma unroll
        for (int r = 0; r < 4; ++r) {
            float s = wc[r][0]*w3[0] + wc[r][1]*w3[1] + wc[r][2]*w3[2] + wc[r][3]*w3[3];
            sV[tid][r] = bv + qm * s;
        }
    }
    __syncthreads();

    if (tid < VD_) {
        const int c = tid;
        float accE[4] = {0.f,0.f,0.f,0.f}, accA[4] = {0.f,0.f,0.f,0.f};
#pragma unroll 4
        for (int k = 0; k < VD_; ++k) {
            float we = W_e[(size_t)k * VD_ + c];
            float wa = W_a[(size_t)k * VD_ + c];
            float4 v = *(const float4*)&sV[k][0];
            float vv[4] = {v.x, v.y, v.z, v.w};
#pragma unroll
            for (int r = 0; r < 4; ++r) {
                accE[r] = fmaf(vv[r], we, accE[r]);
                accA[r] = fmaf(vv[r], wa, accA[r]);
            }
        }
        const float be = b_e[c], ba = b_a[c];
#pragma unroll
        for (int r = 0; r < 4; ++r) {
            const size_t row = (size_t)qi * K_ + r;
            elut[row * VD_ + c] = 1.0f / (1.0f + expf(-(accE[r] + be)));
            alut[row * VD_ + c] = tanhf(accA[r] + ba);
        }
    }
}

// ---------------------------------------------------------------------------
// kB v10: fully-scalar-fed scan. ZERO LDS, zero barriers in the loop.
// q/r read via s_load directly from q_data/r_data (uniform addresses);
// w rows via s_load from clut into two banks reloaded IN PLACE 2 steps
// ahead (no register rotation -> the unavoidable lgkmcnt(0) at first use
// only drains loads >= 1 iteration old = free). e/a keep the 4-deep VMEM
// pipeline (vmcnt is in-order, fine-grained). 2 groups write partial
// reads0/reads1; k4a sums. Scalar loads dual-issue with VALU.
// ---------------------------------------------------------------------------
__global__ __launch_bounds__(512) void kB_scan(
    const int* __restrict__ q_data, const int* __restrict__ r_data,
    const float* __restrict__ init_mem, const float* __restrict__ clut,
    const float* __restrict__ elut, const float* __restrict__ alut,
    float* __restrict__ reads0, float* __restrict__ reads1)
{
    const int b   = blockIdx.x;
    const int tid = threadIdx.x;
    const int j   = tid & 255;
    const int g   = tid >> 8;          // 0 or 1, uniform per wave
    const bool act = (j < VD_);
    const int m0  = __builtin_amdgcn_readfirstlane(g * 25);

    const int* qb = q_data + (size_t)b * S_;
    const int* rr = r_data + (size_t)b * S_;

    float mem[25];
    if (act) {
#pragma unroll
        for (int m = 0; m < 25; ++m) mem[m] = init_mem[(m0 + m) * VD_ + j];
    }

    float* rb = (g == 0 ? reads0 : reads1) + (size_t)b * S_ * VD_;

    // ---- prologue ----
    // eids for steps 0..5 (scalar)
    int q0 = qb[0], q1 = qb[1], q2 = qb[2], q3 = qb[3];
    int r0 = rr[0], r1 = rr[1], r2 = rr[2], r3 = rr[3];

    // e/a 4-deep register pipeline (VMEM, scalar base + j)
    float e0=0,a0=0,e1=0,a1=0,e2=0,a2=0,e3=0,a3=0;
    if (act) {
        const float* p0 = elut + (size_t)(q0*K_ + r0) * VD_;
        const float* p1 = elut + (size_t)(q1*K_ + r1) * VD_;
        const float* p2 = elut + (size_t)(q2*K_ + r2) * VD_;
        const float* p3 = elut + (size_t)(q3*K_ + r3) * VD_;
        const float* s0 = alut + (size_t)(q0*K_ + r0) * VD_;
        const float* s1 = alut + (size_t)(q1*K_ + r1) * VD_;
        const float* s2 = alut + (size_t)(q2*K_ + r2) * VD_;
        const float* s3 = alut + (size_t)(q3*K_ + r3) * VD_;
        e0 = p0[j]; a0 = s0[j];
        e1 = p1[j]; a1 = s1[j];
        e2 = p2[j]; a2 = s2[j];
        e3 = p3[j]; a3 = s3[j];
    }

    // w banks: wA = row for even step s, wB = row for odd step s+1.
    // Reloaded in place at iteration end for s+2 / s+3.
    float wA[25], wB[25];
    {
        const float* c0 = clut + (size_t)q0 * M_ + m0;
        const float* c1 = clut + (size_t)q1 * M_ + m0;
#pragma unroll
        for (int i = 0; i < 25; ++i) { wA[i] = c0[i]; wB[i] = c1[i]; }
    }

    for (int s = 0; s < S_; s += 2) {
        // scalar eids for steps s+4, s+5 (used below for e/a prefetch and
        // next iteration's w reload)
        int q4 = 0, r4 = 0, q5 = 0, r5 = 0;
        if (s + 4 < S_) { q4 = qb[s+4]; r4 = rr[s+4]; }
        if (s + 5 < S_) { q5 = qb[s+5]; r5 = rr[s+5]; }

        // e/a prefetch for s+4, s+5 (consumed 2 iterations later)
        float e4=0,a4=0,e5=0,a5=0;
        if (act && s+4 < S_) {
            const float* pe = elut + (size_t)(q4*K_ + r4) * VD_;
            const float* pa = alut + (size_t)(q4*K_ + r4) * VD_;
            e4 = pe[j]; a4 = pa[j];
        }
        if (act && s+5 < S_) {
            const float* pe = elut + (size_t)(q5*K_ + r5) * VD_;
            const float* pa = alut + (size_t)(q5*K_ + r5) * VD_;
            e5 = pe[j]; a5 = pa[j];
        }

        // step s (uses wA, e0/a0)
        {
            float ra = 0.f, rc = 0.f;
#pragma unroll
            for (int i = 0; i < 25; i += 2) {
                float w0 = wA[i];
                ra = fmaf(w0, mem[i], ra);
                float t0 = fmaf(-e0, mem[i], a0);
                mem[i] = fmaf(w0, t0, mem[i]);
                if (i + 1 < 25) {
                    float w1 = wA[i+1];
                    rc = fmaf(w1, mem[i+1], rc);
                    float t1 = fmaf(-e0, mem[i+1], a0);
                    mem[i+1] = fmaf(w1, t1, mem[i+1]);
                }
            }
            if (act) rb[s * VD_ + j] = ra + rc;
        }
        // step s+1 (uses wB, e1/a1)
        {
            float ra = 0.f, rc = 0.f;
#pragma unroll
            for (int i = 0; i < 25; i += 2) {
                float w0 = wB[i];
                ra = fmaf(w0, mem[i], ra);
                float t0 = fmaf(-e1, mem[i], a1);
                mem[i] = fmaf(w0, t0, mem[i]);
                if (i + 1 < 25) {
                    float w1 = wB[i+1];
                    rc = fmaf(w1, mem[i+1], rc);
                    float t1 = fmaf(-e1, mem[i+1], a1);
                    mem[i+1] = fmaf(w1, t1, mem[i+1]);
                }
            }
            if (act) rb[(s+1) * VD_ + j] = ra + rc;
        }

        // reload w banks in place for steps s+2, s+3 (scalar; waited-for
        // only at next iteration's first use -> latency fully hidden)
        {
            const int qs2 = (s+2 < S_) ? qb[s+2] : 0;
            const int qs3 = (s+3 < S_) ? qb[s+3] : 0;
            const float* cA = clut + (size_t)qs2 * M_ + m0;
            const float* cB = clut + (size_t)qs3 * M_ + m0;
#pragma unroll
            for (int i = 0; i < 25; ++i) { wA[i] = cA[i]; wB[i] = cB[i]; }
        }

        // rotate e/a pipeline (VGPR copies)
        e0 = e2; a0 = a2; e1 = e3; a1 = a3;
        e2 = e4; a2 = a4; e3 = e5; a3 = a5;
    }
}

// ---------------------------------------------------------------------------
// k4a: summary GEMM. Stages sAt = reads0 + reads1 (the two scan partials).
// BT=40 -> 1280 blocks. Writes summary transposed summT[c][tok].
// ---------------------------------------------------------------------------
#define BT4A 40
__global__ __launch_bounds__(256) void k4a_summary(
    const int* __restrict__ q_data, const float* __restrict__ q_tab,
    const float* __restrict__ reads0, const float* __restrict__ reads1,
    const float* __restrict__ W_sum, const float* __restrict__ b_sum,
    float* __restrict__ summT)
{
    __shared__ __align__(16) float sAt[25][44];   // [kk][t], pad 44
    __shared__ __align__(16) float sW[25][52];
    __shared__ int sQ[BT4A];

    const int tid  = threadIdx.x;
    const int tok0 = blockIdx.x * BT4A;
    const int ty = tid / 25;        // 0..9 -> token group of 4
    const int tx = tid % 25;        // col pair
    const bool act = (tid < 250);
    const int t0 = ty * 4;

    if (tid < BT4A) sQ[tid] = q_data[tok0 + tid];

    float acc[4][2];
#pragma unroll
    for (int i = 0; i < 4; ++i) { acc[i][0] = 0.f; acc[i][1] = 0.f; }

    for (int kt = 0; kt < 250; kt += 25) {
        __syncthreads();
        for (int i = tid; i < BT4A * 25; i += 256) {
            int t = i / 25, kk = i % 25;
            float v;
            if (kt < VD_) {
                size_t idx = (size_t)(tok0 + t) * VD_ + kt + kk;
                v = reads0[idx] + reads1[idx];
            } else {
                v = q_tab[(size_t)sQ[t] * KD_ + (kt - VD_) + kk];
            }
            sAt[kk][t] = v;
        }
        for (int i = tid; i < 25 * FD_; i += 256) {
            int kk = i / FD_, col = i % FD_;
            sW[kk][col] = W_sum[(size_t)(kt + kk) * FD_ + col];
        }
        __syncthreads();

        if (act) {
#pragma unroll 5
            for (int kk = 0; kk < 25; ++kk) {
                float2 w = *(const float2*)&sW[kk][2 * tx];
                float4 a0 = *(const float4*)&sAt[kk][t0];
                float av[4] = {a0.x, a0.y, a0.z, a0.w};
#pragma unroll
                for (int i = 0; i < 4; ++i) {
                    acc[i][0] = fmaf(av[i], w.x, acc[i][0]);
                    acc[i][1] = fmaf(av[i], w.y, acc[i][1]);
                }
            }
        }
    }

    if (act) {
        const float b0 = b_sum[2 * tx], b1 = b_sum[2 * tx + 1];
#pragma unroll
        for (int i = 0; i < 4; ++i) {
            const size_t tok = tok0 + t0 + i;
            summT[(size_t)(2 * tx)     * T_ + tok] = tanhf(acc[i][0] + b0);
            summT[(size_t)(2 * tx + 1) * T_ + tok] = tanhf(acc[i][1] + b1);
        }
    }
}

// ---------------------------------------------------------------------------
// k4b: per-token head. One thread per token; summT reads coalesced; W
// vectors wave-uniform; no shfl, no LDS.
// ---------------------------------------------------------------------------
__global__ __launch_bounds__(256) void k4b_head(
    const int* __restrict__ q_data, const float* __restrict__ q_tab,
    const float* __restrict__ summT,
    const float* __restrict__ W_ab, const float* __restrict__ b_ab,
    const float* __restrict__ W_th, const float* __restrict__ b_th,
    const float* __restrict__ W_disc, const float* __restrict__ b_disc,
    float* __restrict__ out)
{
    const int tok = blockIdx.x * 256 + threadIdx.x;
    const int q = q_data[tok];
    const float* qe = q_tab + (size_t)q * KD_;

    float v_ab = 0.f, v_d = 0.f, v_t0 = 0.f, v_t1 = 0.f, v_t2 = 0.f;
#pragma unroll 10
    for (int c = 0; c < FD_; ++c) {
        float s  = summT[(size_t)c * T_ + tok];
        float qv = qe[c];
        v_ab = fmaf(s,  W_ab[c],        v_ab);
        v_d  = fmaf(s,  W_disc[c],      v_d);
        v_d  = fmaf(qv, W_disc[FD_ + c], v_d);
        v_t0 = fmaf(qv, W_th[c * 3 + 0], v_t0);
        v_t1 = fmaf(qv, W_th[c * 3 + 1], v_t1);
        v_t2 = fmaf(qv, W_th[c * 3 + 2], v_t2);
    }

    float theta = 3.0f * (v_ab + b_ab[0]);
    float xd = v_d + b_disc[0];
    float alpha = fmaxf(xd, 0.0f) + log1pf(expf(-fabsf(xd)));
    float beta0 = tanhf(v_t0 + b_th[0]);
    float beta1 = tanhf(v_t1 + b_th[1]);
    float beta2 = tanhf(v_t2 + b_th[2]);
    float c1 = alpha * (theta - beta0);
    float c2 = c1 + alpha * (theta - beta1);
    float c3 = c2 + alpha * (theta - beta2);
    float mx = fmaxf(fmaxf(0.0f, c1), fmaxf(c2, c3));
    float e0 = expf(0.0f - mx), e1 = expf(c1 - mx),
          e2 = expf(c2 - mx), e3 = expf(c3 - mx);
    float s4 = e0 + e1 + e2 + e3;
    float4 o = make_float4(e0 / s4, e1 / s4, e2 / s4, e3 / s4);
    *(float4*)&out[(size_t)tok * 4] = o;
}

// ---------------------------------------------------------------------------
extern "C" void kernel_launch(void* const* d_in, const int* in_sizes, int n_in,
                              void* d_out, int out_size, void* d_ws, size_t ws_size,
                              hipStream_t stream) {
    const int*   q_data   = (const int*)  d_in[0];
    const int*   r_data   = (const int*)  d_in[1];
    const float* q_tab    = (const float*)d_in[2];
    const float* key_mem  = (const float*)d_in[3];
    const float* init_mem = (const float*)d_in[4];
    const float* W_qk     = (const float*)d_in[5];
    const float* b_qk     = (const float*)d_in[6];
    const float* W_v3     = (const float*)d_in[7];
    const float* b_v      = (const float*)d_in[8];
    const float* W_e      = (const float*)d_in[9];
    const float* b_e      = (const float*)d_in[10];
    const float* W_a      = (const float*)d_in[11];
    const float* b_a      = (const float*)d_in[12];
    const float* W_sum    = (const float*)d_in[13];
    const float* b_sum    = (const float*)d_in[14];
    const float* W_ab     = (const float*)d_in[15];
    const float* b_ab     = (const float*)d_in[16];
    const float* W_th     = (const float*)d_in[17];
    const float* b_th     = (const float*)d_in[18];
    const float* W_disc   = (const float*)d_in[19];
    const float* b_disc   = (const float*)d_in[20];

    float* ws     = (float*)d_ws;
    float* reads0 = ws;                                   // T*VD
    float* reads1 = reads0 + (size_t)T_ * VD_;            // T*VD
    float* clut   = reads1 + (size_t)T_ * VD_;            // 401*50
    float* elut   = clut + (size_t)(NQ_ + 1) * M_;        // 1604*200
    float* alut   = elut + (size_t)NE_ * VD_;             // 1604*200
    float* summT  = alut + (size_t)NE_ * VD_;             // 50*T
    // total ~23.7M floats = 95 MB

    kA1_corrlut<<<(NQ_ + 4) / 4, 256, 0, stream>>>(q_tab, key_mem, W_qk, b_qk, clut);
    kA2_ealut<<<NQ_ + 1, 256, 0, stream>>>(W_v3, b_v, W_e, b_e, W_a, b_a, elut, alut);
    kB_scan<<<B_, 512, 0, stream>>>(q_data, r_data, init_mem, clut, elut, alut,
                                    reads0, reads1);
    k4a_summary<<<T_ / BT4A, 256, 0, stream>>>(q_data, q_tab, reads0, reads1,
                                               W_sum, b_sum, summT);
    k4b_head<<<T_ / 256, 256, 0, stream>>>(q_data, q_tab, summT,
                                           W_ab, b_ab, W_th, b_th, W_disc, b_disc,
                                           (float*)d_out);
}